// Round 2
// baseline (50.984 us; speedup 1.0000x reference)
//
#include <hip/hip_runtime.h>

// DeepWalk hierarchical-softmax forward.
// Inputs: center[B] i32, context[B] i32, embeddings[2^19][128] f32,
//         probs_tensor[2^20][128] f32. Output: [B] f32 = -sum_l logsigmoid(sign*dot).
//
// Layout: 32 lanes per batch element (2 elements per wave). Each lane owns
// 4 consecutive floats (float4, 16B) of the 128-wide row -> a half-wave's
// loads cover one 512B row exactly (full cacheline utilization on gathers).
// All 18 level rows are loaded before any reduction so up to 18 global loads
// are in flight per lane (latency hiding via vmcnt pipelining).

#define HS_NUM_NODES (1 << 19)
#define HS_LVLS 18          // levels i = 1 .. 18  (L-1 where L = 19)

__global__ __launch_bounds__(256) void hs_fwd_kernel(
    const int* __restrict__ center,
    const int* __restrict__ context,
    const float* __restrict__ emb,
    const float* __restrict__ probs,
    float* __restrict__ out,
    int B)
{
    const int tid  = blockIdx.x * blockDim.x + threadIdx.x;
    const int elem = tid >> 5;                 // one element per 32-lane group
    if (elem >= B) return;
    const int sub = threadIdx.x & 31;          // lane within the 32-group

    const int c   = center[elem];
    const int ctx = context[elem] + HS_NUM_NODES;

    // center embedding fragment: 4 floats per lane
    const float4 ec =
        *reinterpret_cast<const float4*>(emb + (size_t)c * 128 + sub * 4);

    // Issue all 18 gathers first (load-all-then-compute: deep MLP pipeline).
    float4 p[HS_LVLS];
    int    node[HS_LVLS];
#pragma unroll
    for (int i = 0; i < HS_LVLS; ++i) {
        node[i] = ctx >> (i + 1);
        p[i] = *reinterpret_cast<const float4*>(
            probs + (size_t)node[i] * 128 + sub * 4);
    }

    float acc = 0.f;
#pragma unroll
    for (int i = 0; i < HS_LVLS; ++i) {
        float partial = p[i].x * ec.x + p[i].y * ec.y
                      + p[i].z * ec.z + p[i].w * ec.w;
        // reduce across the 32-lane group (xor masks <=16 never cross halves)
#pragma unroll
        for (int m = 16; m; m >>= 1) partial += __shfl_xor(partial, m, 64);
        const float x = (node[i] & 1) ? -partial : partial;
        // stable log-sigmoid: min(x,0) - log(1 + exp(-|x|))
        acc += fminf(x, 0.f) - __logf(1.f + __expf(-fabsf(x)));
    }

    if (sub == 0) out[elem] = -acc;
}

extern "C" void kernel_launch(void* const* d_in, const int* in_sizes, int n_in,
                              void* d_out, int out_size, void* d_ws, size_t ws_size,
                              hipStream_t stream) {
    const int*   center  = (const int*)d_in[0];
    const int*   context = (const int*)d_in[1];
    const float* emb     = (const float*)d_in[2];
    const float* probs   = (const float*)d_in[3];
    float*       out     = (float*)d_out;

    const int B = in_sizes[0];                 // 65536
    const int threads = 256;                   // 8 elements / block
    const int blocks  = (B * 32 + threads - 1) / threads;
    hs_fwd_kernel<<<blocks, threads, 0, stream>>>(center, context, emb, probs,
                                                  out, B);
}

// Round 3
// 48.225 us; speedup vs baseline: 1.0572x; 1.0572x over previous
//
#include <hip/hip_runtime.h>

// DeepWalk hierarchical-softmax forward — round 3.
// Change vs R2: the 18 per-level 5-step shuffle reductions (90 cross-lane ops
// + 36 redundant transcendental issues per wave) are replaced by ONE
// multi-value fold butterfly (5 steps, ~20 shuffles) that leaves lane l
// holding the dot product for level l; log-sigmoid is then issued once
// across lanes instead of 18 times.
//
// Layout unchanged: 32 lanes per batch element (2 per wave); each lane owns
// 16B (float4) of the 512B row -> full-cacheline gathers; all 18 level rows
// are loaded before any compute (deep vmcnt pipeline).

#define HS_NUM_NODES (1 << 19)
#define HS_LVLS 18          // levels i = 1 .. 18  (L = 19)

// One fold step of the multi-value reduction: N values per lane -> ceil(N/2),
// folding the lowest surviving level-bit into lane-bit log2(M).
// After all steps, lane l holds sum-over-lanes of value[l].
template <int N, int M>
__device__ inline void fold_step(float* w, int sub) {
    const bool hi = (sub & M) != 0;
    constexpr int NN = (N + 1) / 2;
#pragma unroll
    for (int k = 0; k < NN; ++k) {
        const float a = w[2 * k];
        const float b = (2 * k + 1 < N) ? w[2 * k + 1] : 0.f;
        const float keep = hi ? b : a;
        const float send = hi ? a : b;
        w[k] = keep + __shfl_xor(send, M, 64);   // M<=16: never crosses halves
    }
}

__global__ __launch_bounds__(256) void hs_fwd_kernel(
    const int* __restrict__ center,
    const int* __restrict__ context,
    const float* __restrict__ emb,
    const float* __restrict__ probs,
    float* __restrict__ out,
    int B)
{
    const int tid  = blockIdx.x * blockDim.x + threadIdx.x;
    const int elem = tid >> 5;                 // one element per 32-lane group
    if (elem >= B) return;
    const int sub = threadIdx.x & 31;

    const int c   = center[elem];
    const int ctx = context[elem] + HS_NUM_NODES;

    const float4 ec =
        *reinterpret_cast<const float4*>(emb + (size_t)c * 128 + sub * 4);

    // Issue all 18 gathers before any compute.
    float4 p[HS_LVLS];
#pragma unroll
    for (int i = 0; i < HS_LVLS; ++i) {
        const int node = ctx >> (i + 1);
        p[i] = *reinterpret_cast<const float4*>(
            probs + (size_t)node * 128 + sub * 4);
    }

    // Per-lane partial dot for each level.
    float w[HS_LVLS];
#pragma unroll
    for (int i = 0; i < HS_LVLS; ++i)
        w[i] = p[i].x * ec.x + p[i].y * ec.y + p[i].z * ec.z + p[i].w * ec.w;

    // Multi-value butterfly: 18 -> 9 -> 5 -> 3 -> 2 -> 1 values per lane.
    // Missing slots enter as 0. Lane l ends holding S_l = full dot of level l
    // (lanes 18..31 hold 0-sums, masked below).
    fold_step<18, 1>(w, sub);
    fold_step<9,  2>(w, sub);
    fold_step<5,  4>(w, sub);
    fold_step<3,  8>(w, sub);
    fold_step<2, 16>(w, sub);

    // Lane l handles level l: sign from parity of node = ctx >> (l+1).
    const int sh   = (sub < HS_LVLS) ? (sub + 1) : 1;   // clamp, masked anyway
    const int node = ctx >> sh;
    const float S  = w[0];
    const float x  = (node & 1) ? -S : S;
    // stable log-sigmoid, issued ONCE for all 18 levels in parallel
    float ls = fminf(x, 0.f) - __logf(1.f + __expf(-fabsf(x)));
    ls = (sub < HS_LVLS) ? ls : 0.f;

    // Sum the 18 per-level terms across the 32-lane group.
    float acc = ls;
#pragma unroll
    for (int m = 16; m; m >>= 1) acc += __shfl_xor(acc, m, 64);

    if (sub == 0) out[elem] = -acc;
}

extern "C" void kernel_launch(void* const* d_in, const int* in_sizes, int n_in,
                              void* d_out, int out_size, void* d_ws, size_t ws_size,
                              hipStream_t stream) {
    const int*   center  = (const int*)d_in[0];
    const int*   context = (const int*)d_in[1];
    const float* emb     = (const float*)d_in[2];
    const float* probs   = (const float*)d_in[3];
    float*       out     = (float*)d_out;

    const int B = in_sizes[0];                 // 65536
    const int threads = 256;                   // 8 elements / block
    const int blocks  = (B * 32 + threads - 1) / threads;
    hs_fwd_kernel<<<blocks, threads, 0, stream>>>(center, context, emb, probs,
                                                  out, B);
}